// Round 2
// baseline (696.582 us; speedup 1.0000x reference)
//
#include <hip/hip_runtime.h>
#include <hip/hip_bf16.h>

// Problem constants (B=4,T=2048,M=1024,E=8,H=4096) — fp32 in/out
#define S_TOK 8192
#define MDIM  1024
#define EXP   8
#define HDIM  4096
#define CAP   1024   // s // E, capacity_factor = 1.0

typedef __attribute__((ext_vector_type(8))) short short8;
typedef __attribute__((ext_vector_type(4))) float floatx4;

__device__ __forceinline__ unsigned short f2b(float f) {
    union { float f; unsigned int i; } v; v.f = f;
    unsigned int r = v.i + 0x7fffu + ((v.i >> 16) & 1u);  // RNE
    return (unsigned short)(r >> 16);
}
__device__ __forceinline__ float b2f(unsigned short u) {
    union { unsigned int i; float f; } v; v.i = ((unsigned int)u) << 16; return v.f;
}

// ---------------- Kernel 1: gating (pure fp32 — argmax must match np ref) ----
__global__ __launch_bounds__(256) void gate_kernel(
    const float* __restrict__ x, const float* __restrict__ wg,
    float* __restrict__ gates8, int* __restrict__ token_expert)
{
    const int wave = threadIdx.x >> 6, lane = threadIdx.x & 63;
    const int s = blockIdx.x * 4 + wave;

    const float* xr = x + (size_t)s * MDIM + lane * 16;
    float xv[16];
#pragma unroll
    for (int q = 0; q < 4; ++q) *(float4*)(xv + q * 4) = *(const float4*)(xr + q * 4);

    float acc[EXP];
#pragma unroll
    for (int e = 0; e < EXP; ++e) acc[e] = 0.f;
    const int m0 = lane * 16;
#pragma unroll
    for (int j = 0; j < 16; ++j) {
        const float xm = xv[j];
        const float* wr = wg + (size_t)(m0 + j) * EXP;
        float4 w0 = *(const float4*)(wr);
        float4 w1v = *(const float4*)(wr + 4);
        acc[0] += xm * w0.x; acc[1] += xm * w0.y; acc[2] += xm * w0.z; acc[3] += xm * w0.w;
        acc[4] += xm * w1v.x; acc[5] += xm * w1v.y; acc[6] += xm * w1v.z; acc[7] += xm * w1v.w;
    }
#pragma unroll
    for (int e = 0; e < EXP; ++e) {
#pragma unroll
        for (int off = 32; off > 0; off >>= 1)
            acc[e] += __shfl_down(acc[e], off);
    }
    if (lane == 0) {
        float mx = acc[0]; int idx = 0;
#pragma unroll
        for (int e = 1; e < EXP; ++e) if (acc[e] > mx) { mx = acc[e]; idx = e; }  // first-max = jnp.argmax
        float g[EXP]; float sum = 0.f;
#pragma unroll
        for (int e = 0; e < EXP; ++e) { g[e] = expf(acc[e] - mx); sum += g[e]; }
        float inv = 1.f / sum;
#pragma unroll
        for (int e = 0; e < EXP; ++e) gates8[(size_t)s * EXP + e] = g[e] * inv;
        token_expert[s] = idx;
    }
}

// ---------------- Kernel 2: scan / slot assignment / l_aux ----------------
__global__ __launch_bounds__(256) void scan_kernel(
    const float* __restrict__ gates8, const int* __restrict__ token_expert,
    int* __restrict__ slot_token, float* __restrict__ slot_gate,
    float* __restrict__ laux_out)
{
    __shared__ int   cnt[256][EXP];
    __shared__ float fsum[256][EXP];
    __shared__ int   tot[EXP];
    const int t = threadIdx.x;

    for (int i = t; i < EXP * CAP; i += 256) slot_token[i] = -1;

    int local[EXP];
#pragma unroll
    for (int e = 0; e < EXP; ++e) local[e] = 0;
    const int s0 = t * 32;
    for (int j = 0; j < 32; ++j) local[token_expert[s0 + j]]++;
#pragma unroll
    for (int e = 0; e < EXP; ++e) cnt[t][e] = local[e];
    __syncthreads();

    if (t < EXP) {  // exclusive scan over 256 chunks for expert t
        int run = 0;
        for (int i = 0; i < 256; ++i) { int v = cnt[i][t]; cnt[i][t] = run; run += v; }
        tot[t] = run;  // pre-drop count -> ce
    }
    __syncthreads();

    int off[EXP];
#pragma unroll
    for (int e = 0; e < EXP; ++e) off[e] = cnt[t][e];
    for (int j = 0; j < 32; ++j) {
        int s = s0 + j;
        int e = token_expert[s];
        int loc = off[e]++;
        if (loc < CAP) {
            int slot = e * CAP + loc;
            slot_token[slot] = s;
            slot_gate[slot]  = gates8[(size_t)s * EXP + e];
        }
    }

    // me = column means of gates8
    float ms[EXP];
#pragma unroll
    for (int e = 0; e < EXP; ++e) ms[e] = 0.f;
    for (int j = 0; j < 32; ++j) {
        const float* g = gates8 + (size_t)(s0 + j) * EXP;
#pragma unroll
        for (int e = 0; e < EXP; ++e) ms[e] += g[e];
    }
#pragma unroll
    for (int e = 0; e < EXP; ++e) fsum[t][e] = ms[e];
    __syncthreads();
    for (int st = 128; st > 0; st >>= 1) {
        if (t < st) {
#pragma unroll
            for (int e = 0; e < EXP; ++e) fsum[t][e] += fsum[t + st][e];
        }
        __syncthreads();
    }
    if (t == 0) {
        float l = 0.f;
#pragma unroll
        for (int e = 0; e < EXP; ++e)
            l += (fsum[0][e] / (float)S_TOK) * ((float)tot[e] / (float)S_TOK);
        laux_out[0] = l * (float)EXP;
    }
}

// ---------------- Kernel 3/4: expert GEMMs ----------------
// out[I=1024, N] = A[I, K] @ B[K, N] per expert (blockIdx.z), bf16 MFMA.
// GATHER: A rows gathered from fp32 x via slot_token (zeros for empty slots),
//         converted to bf16 during staging. !GATHER: A is bf16 h in ws.
// B (w1/w2) is fp32, converted to bf16 during staging.
// SCATTER: out row gi -> token slot_token[e*CAP+gi]; write fp32 gate*val to d_out.
// !SCATTER: relu + bf16 store to h.
template<int KSTEPS, int N, bool GATHER, bool SCATTER>
__global__ __launch_bounds__(256) void ffn_gemm(
    const void* __restrict__ Agv, const float* __restrict__ Bg,
    void* __restrict__ Outv,
    const int* __restrict__ slot_token, const float* __restrict__ slot_gate)
{
    constexpr int K = KSTEPS * 32;
    const int e  = blockIdx.z;
    const int ib = blockIdx.y * 128;
    const int nb = blockIdx.x * 128;
    const int t  = threadIdx.x;

    __shared__ unsigned short As[128 * 40];   // [i][k], +8 pad
    __shared__ unsigned short Bs[32 * 136];   // [k][n], +8 pad

    const float* B = Bg + (size_t)e * K * N;

    // A staging assignment: 2 threads per row, 16 elems each
    const int arow  = t >> 1;
    const int ahalf = t & 1;
    const float* ArowF = nullptr;
    const unsigned short* ArowH = nullptr;
    bool avalid = true;
    if (GATHER) {
        int tok = slot_token[e * CAP + ib + arow];
        avalid = (tok >= 0);
        ArowF = (const float*)Agv + (size_t)(avalid ? tok : 0) * K;
    } else {
        ArowH = (const unsigned short*)Agv + ((size_t)e * 1024 + ib + arow) * K;
    }
    // B staging: 8 threads per k-row, 16 n each
    const int bk  = t >> 3;
    const int bn0 = (t & 7) * 16;
    const float* Bptr = B + (size_t)bk * N + nb + bn0;

    const int lane = t & 63, wave = t >> 6;
    const int quad = lane >> 4, l15 = lane & 15;
    const int wr = wave >> 1, wc = wave & 1;

    floatx4 acc[4][4];
#pragma unroll
    for (int r = 0; r < 4; ++r)
#pragma unroll
        for (int c = 0; c < 4; ++c)
            acc[r][c] = (floatx4){0.f, 0.f, 0.f, 0.f};

    for (int kb = 0; kb < KSTEPS; ++kb) {
        const int k0 = kb * 32;

        // ---- A tile ----
        unsigned short av[16];
        if (GATHER) {
            if (avalid) {
                const float4* p = (const float4*)(ArowF + k0 + ahalf * 16);
                float4 f0 = p[0], f1 = p[1], f2 = p[2], f3 = p[3];
                const float fa[16] = {f0.x,f0.y,f0.z,f0.w, f1.x,f1.y,f1.z,f1.w,
                                      f2.x,f2.y,f2.z,f2.w, f3.x,f3.y,f3.z,f3.w};
#pragma unroll
                for (int j = 0; j < 16; ++j) av[j] = f2b(fa[j]);
            } else {
#pragma unroll
                for (int j = 0; j < 16; ++j) av[j] = 0;
            }
        } else {
            const int4* p = (const int4*)(ArowH + k0 + ahalf * 16);
            *(int4*)(av)     = p[0];
            *(int4*)(av + 8) = p[1];
        }

        // ---- B tile (fp32 -> bf16) ----
        unsigned short bv[16];
        {
            const float4* q = (const float4*)(Bptr + (size_t)k0 * N);
            float4 f0 = q[0], f1 = q[1], f2 = q[2], f3 = q[3];
            const float fb[16] = {f0.x,f0.y,f0.z,f0.w, f1.x,f1.y,f1.z,f1.w,
                                  f2.x,f2.y,f2.z,f2.w, f3.x,f3.y,f3.z,f3.w};
#pragma unroll
            for (int j = 0; j < 16; ++j) bv[j] = f2b(fb[j]);
        }

        *(int4*)&As[arow * 40 + ahalf * 16]     = *(int4*)(av);
        *(int4*)&As[arow * 40 + ahalf * 16 + 8] = *(int4*)(av + 8);
        *(int4*)&Bs[bk * 136 + bn0]             = *(int4*)(bv);
        *(int4*)&Bs[bk * 136 + bn0 + 8]         = *(int4*)(bv + 8);
        __syncthreads();

        short8 af[4];
#pragma unroll
        for (int r = 0; r < 4; ++r)
            af[r] = *(const short8*)&As[(wr * 64 + r * 16 + l15) * 40 + quad * 8];
        short8 bfr[4];
#pragma unroll
        for (int c = 0; c < 4; ++c) {
#pragma unroll
            for (int j = 0; j < 8; ++j)
                bfr[c][j] = (short)Bs[(quad * 8 + j) * 136 + wc * 64 + c * 16 + l15];
        }
#pragma unroll
        for (int r = 0; r < 4; ++r)
#pragma unroll
            for (int c = 0; c < 4; ++c)
                acc[r][c] = __builtin_amdgcn_mfma_f32_16x16x32_bf16(af[r], bfr[c], acc[r][c], 0, 0, 0);
        __syncthreads();
    }

    // epilogue: C/D layout col=lane&15, row=quad*4+reg
#pragma unroll
    for (int r = 0; r < 4; ++r) {
#pragma unroll
        for (int reg = 0; reg < 4; ++reg) {
            const int gi = ib + wr * 64 + r * 16 + quad * 4 + reg;
            if (SCATTER) {
                const int slot = e * CAP + gi;
                const int tok = slot_token[slot];
                if (tok >= 0) {
                    const float gsc = slot_gate[slot];
                    float* Out = (float*)Outv;
#pragma unroll
                    for (int c = 0; c < 4; ++c) {
                        const int gn = nb + wc * 64 + c * 16 + l15;
                        Out[(size_t)tok * N + gn] = gsc * acc[r][c][reg];
                    }
                }
            } else {
                unsigned short* Out = (unsigned short*)Outv;
#pragma unroll
                for (int c = 0; c < 4; ++c) {
                    const int gn = nb + wc * 64 + c * 16 + l15;
                    float v = fmaxf(acc[r][c][reg], 0.f);  // relu
                    Out[((size_t)e * 1024 + gi) * N + gn] = f2b(v);
                }
            }
        }
    }
}

extern "C" void kernel_launch(void* const* d_in, const int* in_sizes, int n_in,
                              void* d_out, int out_size, void* d_ws, size_t ws_size,
                              hipStream_t stream)
{
    const float* x  = (const float*)d_in[0];   // [8192,1024] fp32
    const float* wg = (const float*)d_in[1];   // [1024,8]    fp32
    const float* w1 = (const float*)d_in[2];   // [8,1024,4096] fp32
    const float* w2 = (const float*)d_in[3];   // [8,4096,1024] fp32
    float* out = (float*)d_out;                // 8388608 out + 1 l_aux, fp32

    char* ws = (char*)d_ws;
    float*          gates8       = (float*)(ws);                   // 256 KB
    int*            token_expert = (int*)(ws + 262144);            // 32 KB
    int*            slot_token   = (int*)(ws + 294912);            // 32 KB
    float*          slot_gate    = (float*)(ws + 327680);          // 32 KB
    unsigned short* h            = (unsigned short*)(ws + 360448); // [8,1024,4096] bf16, 64 MB

    // zero output (dropped tokens must be 0; scatter fills the rest)
    hipMemsetAsync(d_out, 0, (size_t)out_size * 4, stream);

    gate_kernel<<<dim3(S_TOK / 4), dim3(256), 0, stream>>>(x, wg, gates8, token_expert);
    scan_kernel<<<dim3(1), dim3(256), 0, stream>>>(gates8, token_expert, slot_token, slot_gate,
                                                   out + (size_t)S_TOK * MDIM);
    // gemm1: h[e] = relu(gather(x) @ w1[e])   I=1024,K=1024,N=4096
    ffn_gemm<32, HDIM, true, false><<<dim3(HDIM / 128, CAP / 128, EXP), dim3(256), 0, stream>>>(
        x, w1, h, slot_token, slot_gate);
    // gemm2: out[tok] = gate * (h[e] @ w2[e]) I=1024,K=4096,N=1024, scatter
    ffn_gemm<128, MDIM, false, true><<<dim3(MDIM / 128, CAP / 128, EXP), dim3(256), 0, stream>>>(
        h, w2, out, slot_token, slot_gate);
}

// Round 3
// 632.277 us; speedup vs baseline: 1.1017x; 1.1017x over previous
//
#include <hip/hip_runtime.h>
#include <hip/hip_bf16.h>

// Problem constants (B=4,T=2048,M=1024,E=8,H=4096) — fp32 in/out
#define S_TOK 8192
#define MDIM  1024
#define EXP   8
#define HDIM  4096
#define CAP   1024   // s // E, capacity_factor = 1.0

typedef __attribute__((ext_vector_type(8))) short short8;
typedef __attribute__((ext_vector_type(4))) float floatx4;

__device__ __forceinline__ unsigned short f2b(float f) {
    union { float f; unsigned int i; } v; v.f = f;
    unsigned int r = v.i + 0x7fffu + ((v.i >> 16) & 1u);  // RNE
    return (unsigned short)(r >> 16);
}

// ---------------- Kernel 1: gating (pure fp32 — argmax must match np ref) ----
__global__ __launch_bounds__(256) void gate_kernel(
    const float* __restrict__ x, const float* __restrict__ wg,
    float* __restrict__ gates8, int* __restrict__ token_expert)
{
    const int wave = threadIdx.x >> 6, lane = threadIdx.x & 63;
    const int s = blockIdx.x * 4 + wave;

    const float* xr = x + (size_t)s * MDIM + lane * 16;
    float xv[16];
#pragma unroll
    for (int q = 0; q < 4; ++q) *(float4*)(xv + q * 4) = *(const float4*)(xr + q * 4);

    float acc[EXP];
#pragma unroll
    for (int e = 0; e < EXP; ++e) acc[e] = 0.f;
    const int m0 = lane * 16;
#pragma unroll
    for (int j = 0; j < 16; ++j) {
        const float xm = xv[j];
        const float* wr = wg + (size_t)(m0 + j) * EXP;
        float4 w0 = *(const float4*)(wr);
        float4 w1v = *(const float4*)(wr + 4);
        acc[0] += xm * w0.x; acc[1] += xm * w0.y; acc[2] += xm * w0.z; acc[3] += xm * w0.w;
        acc[4] += xm * w1v.x; acc[5] += xm * w1v.y; acc[6] += xm * w1v.z; acc[7] += xm * w1v.w;
    }
#pragma unroll
    for (int e = 0; e < EXP; ++e) {
#pragma unroll
        for (int off = 32; off > 0; off >>= 1)
            acc[e] += __shfl_down(acc[e], off);
    }
    if (lane == 0) {
        float mx = acc[0]; int idx = 0;
#pragma unroll
        for (int e = 1; e < EXP; ++e) if (acc[e] > mx) { mx = acc[e]; idx = e; }
        float g[EXP]; float sum = 0.f;
#pragma unroll
        for (int e = 0; e < EXP; ++e) { g[e] = expf(acc[e] - mx); sum += g[e]; }
        float inv = 1.f / sum;
#pragma unroll
        for (int e = 0; e < EXP; ++e) gates8[(size_t)s * EXP + e] = g[e] * inv;
        token_expert[s] = idx;
    }
}

// ---------------- Kernel 2: scan / slot assignment / l_aux ----------------
__global__ __launch_bounds__(256) void scan_kernel(
    const float* __restrict__ gates8, const int* __restrict__ token_expert,
    int* __restrict__ slot_token, float* __restrict__ slot_gate,
    float* __restrict__ laux_out)
{
    __shared__ int   cnt[256][EXP];
    __shared__ float fsum[256][EXP];
    __shared__ int   tot[EXP];
    const int t = threadIdx.x;

    for (int i = t; i < EXP * CAP; i += 256) slot_token[i] = -1;

    int local[EXP];
#pragma unroll
    for (int e = 0; e < EXP; ++e) local[e] = 0;
    const int s0 = t * 32;
    for (int j = 0; j < 32; ++j) local[token_expert[s0 + j]]++;
#pragma unroll
    for (int e = 0; e < EXP; ++e) cnt[t][e] = local[e];
    __syncthreads();

    if (t < EXP) {
        int run = 0;
        for (int i = 0; i < 256; ++i) { int v = cnt[i][t]; cnt[i][t] = run; run += v; }
        tot[t] = run;  // pre-drop count -> ce
    }
    __syncthreads();

    int off[EXP];
#pragma unroll
    for (int e = 0; e < EXP; ++e) off[e] = cnt[t][e];
    for (int j = 0; j < 32; ++j) {
        int s = s0 + j;
        int e = token_expert[s];
        int loc = off[e]++;
        if (loc < CAP) {
            int slot = e * CAP + loc;
            slot_token[slot] = s;
            slot_gate[slot]  = gates8[(size_t)s * EXP + e];
        }
    }

    float ms[EXP];
#pragma unroll
    for (int e = 0; e < EXP; ++e) ms[e] = 0.f;
    for (int j = 0; j < 32; ++j) {
        const float* g = gates8 + (size_t)(s0 + j) * EXP;
#pragma unroll
        for (int e = 0; e < EXP; ++e) ms[e] += g[e];
    }
#pragma unroll
    for (int e = 0; e < EXP; ++e) fsum[t][e] = ms[e];
    __syncthreads();
    for (int st = 128; st > 0; st >>= 1) {
        if (t < st) {
#pragma unroll
            for (int e = 0; e < EXP; ++e) fsum[t][e] += fsum[t + st][e];
        }
        __syncthreads();
    }
    if (t == 0) {
        float l = 0.f;
#pragma unroll
        for (int e = 0; e < EXP; ++e)
            l += (fsum[0][e] / (float)S_TOK) * ((float)tot[e] / (float)S_TOK);
        laux_out[0] = l * (float)EXP;
    }
}

// ---------------- Kernel 2b: gather + fp32->bf16 dispatch buffer ----------
// xd[slot][m] = bf16(x[slot_token[slot]][m]) or 0 for empty slots.
__global__ __launch_bounds__(256) void dispatch_cvt(
    const float* __restrict__ x, const int* __restrict__ slot_token,
    unsigned short* __restrict__ xd)
{
    const int slot = blockIdx.x, t = threadIdx.x;
    const int tok = slot_token[slot];
    unsigned short v[4];
    if (tok >= 0) {
        float4 f = *(const float4*)(x + (size_t)tok * MDIM + t * 4);
        v[0] = f2b(f.x); v[1] = f2b(f.y); v[2] = f2b(f.z); v[3] = f2b(f.w);
    } else {
        v[0] = v[1] = v[2] = v[3] = 0;
    }
    *(int2*)(xd + (size_t)slot * MDIM + t * 4) = *(const int2*)v;
}

// ---------------- Kernel 2c: transpose + cvt weights -----------------------
// src fp32 [e][R][C] -> dst bf16 [e][C][R].  64x64 tile per block.
__global__ __launch_bounds__(256) void transpose_cvt(
    const float* __restrict__ src, unsigned short* __restrict__ dst, int R, int C)
{
    __shared__ unsigned short Ls[64 * 72];
    const size_t eo = (size_t)blockIdx.z * R * C;
    src += eo; dst += eo;
    const int C0 = blockIdx.x * 64, R0 = blockIdx.y * 64;
    const int t = threadIdx.x;
    {
        const int r = t >> 2, c0 = (t & 3) * 16;
        const float* p = src + (size_t)(R0 + r) * C + C0 + c0;
        float f[16];
#pragma unroll
        for (int q = 0; q < 4; ++q) *(float4*)(f + q * 4) = ((const float4*)p)[q];
#pragma unroll
        for (int j = 0; j < 16; ++j) Ls[(c0 + j) * 72 + r] = f2b(f[j]);
    }
    __syncthreads();
    {
        const int c = t >> 2, m0 = (t & 3) * 16;
        int4 v0 = *(const int4*)&Ls[c * 72 + m0];
        int4 v1 = *(const int4*)&Ls[c * 72 + m0 + 8];
        int4* q = (int4*)(dst + (size_t)(C0 + c) * R + R0 + m0);
        q[0] = v0; q[1] = v1;
    }
}

// ---------------- Fast expert GEMM (both operands bf16 k-fast) -------------
// out[I=1024, N] = A[I, K] @ BT[N, K]^T per expert (blockIdx.z), bf16 MFMA.
// SCATTER: out row gi -> token slot_token[e*CAP+gi]; fp32 gate*val to d_out.
// !SCATTER: relu + bf16 store (row stride N).
template<int KSTEPS, int N, bool SCATTER>
__global__ __launch_bounds__(256) void ffn_gemm_fast(
    const unsigned short* __restrict__ Ab, const unsigned short* __restrict__ BT,
    void* __restrict__ Outv,
    const int* __restrict__ slot_token, const float* __restrict__ slot_gate)
{
    constexpr int K = KSTEPS * 32;
    const int e  = blockIdx.z;
    const int ib = blockIdx.y * 128;
    const int nb = blockIdx.x * 128;
    const int t  = threadIdx.x;

    __shared__ unsigned short As[128 * 40];   // [i][k], pad->stride 40 (conflict-free b128)
    __shared__ unsigned short Bs[128 * 40];   // [n][k], pad->stride 40

    const int row = t >> 1, half = t & 1;
    const unsigned short* Ap = Ab + ((size_t)e * CAP + ib + row) * K + half * 16;
    const unsigned short* Bp = BT + ((size_t)e * N   + nb + row) * K + half * 16;

    const int lane = t & 63, wave = t >> 6;
    const int quad = lane >> 4, l15 = lane & 15;
    const int wr = wave >> 1, wc = wave & 1;

    floatx4 acc[4][4];
#pragma unroll
    for (int r = 0; r < 4; ++r)
#pragma unroll
        for (int c = 0; c < 4; ++c)
            acc[r][c] = (floatx4){0.f, 0.f, 0.f, 0.f};

    for (int kb = 0; kb < KSTEPS; ++kb) {
        const int k0 = kb * 32;
        int4 a0 = ((const int4*)(Ap + k0))[0];
        int4 a1 = ((const int4*)(Ap + k0))[1];
        int4 b0 = ((const int4*)(Bp + k0))[0];
        int4 b1 = ((const int4*)(Bp + k0))[1];

        *(int4*)&As[row * 40 + half * 16]     = a0;
        *(int4*)&As[row * 40 + half * 16 + 8] = a1;
        *(int4*)&Bs[row * 40 + half * 16]     = b0;
        *(int4*)&Bs[row * 40 + half * 16 + 8] = b1;
        __syncthreads();

        short8 af[4], bfr[4];
#pragma unroll
        for (int r = 0; r < 4; ++r)
            af[r] = *(const short8*)&As[(wr * 64 + r * 16 + l15) * 40 + quad * 8];
#pragma unroll
        for (int c = 0; c < 4; ++c)
            bfr[c] = *(const short8*)&Bs[(wc * 64 + c * 16 + l15) * 40 + quad * 8];
#pragma unroll
        for (int r = 0; r < 4; ++r)
#pragma unroll
            for (int c = 0; c < 4; ++c)
                acc[r][c] = __builtin_amdgcn_mfma_f32_16x16x32_bf16(af[r], bfr[c], acc[r][c], 0, 0, 0);
        __syncthreads();
    }

    // epilogue: C/D layout col=lane&15, row=quad*4+reg
#pragma unroll
    for (int r = 0; r < 4; ++r) {
#pragma unroll
        for (int reg = 0; reg < 4; ++reg) {
            const int gi = ib + wr * 64 + r * 16 + quad * 4 + reg;
            if (SCATTER) {
                const int slot = e * CAP + gi;
                const int tok = slot_token[slot];
                if (tok >= 0) {
                    const float gsc = slot_gate[slot];
                    float* Out = (float*)Outv;
#pragma unroll
                    for (int c = 0; c < 4; ++c) {
                        const int gn = nb + wc * 64 + c * 16 + l15;
                        Out[(size_t)tok * N + gn] = gsc * acc[r][c][reg];
                    }
                }
            } else {
                unsigned short* Out = (unsigned short*)Outv;
#pragma unroll
                for (int c = 0; c < 4; ++c) {
                    const int gn = nb + wc * 64 + c * 16 + l15;
                    Out[((size_t)e * CAP + gi) * N + gn] = f2b(fmaxf(acc[r][c][reg], 0.f));
                }
            }
        }
    }
}

// ---------------- Fallback (R2, proven): fused-cvt GEMM --------------------
template<int KSTEPS, int N, bool GATHER, bool SCATTER>
__global__ __launch_bounds__(256) void ffn_gemm_slow(
    const void* __restrict__ Agv, const float* __restrict__ Bg,
    void* __restrict__ Outv,
    const int* __restrict__ slot_token, const float* __restrict__ slot_gate)
{
    constexpr int K = KSTEPS * 32;
    const int e  = blockIdx.z;
    const int ib = blockIdx.y * 128;
    const int nb = blockIdx.x * 128;
    const int t  = threadIdx.x;

    __shared__ unsigned short As[128 * 40];
    __shared__ unsigned short Bs[32 * 136];

    const float* B = Bg + (size_t)e * K * N;
    const int arow  = t >> 1;
    const int ahalf = t & 1;
    const float* ArowF = nullptr;
    const unsigned short* ArowH = nullptr;
    bool avalid = true;
    if (GATHER) {
        int tok = slot_token[e * CAP + ib + arow];
        avalid = (tok >= 0);
        ArowF = (const float*)Agv + (size_t)(avalid ? tok : 0) * K;
    } else {
        ArowH = (const unsigned short*)Agv + ((size_t)e * CAP + ib + arow) * K;
    }
    const int bk  = t >> 3;
    const int bn0 = (t & 7) * 16;
    const float* Bptr = B + (size_t)bk * N + nb + bn0;

    const int lane = t & 63, wave = t >> 6;
    const int quad = lane >> 4, l15 = lane & 15;
    const int wr = wave >> 1, wc = wave & 1;

    floatx4 acc[4][4];
#pragma unroll
    for (int r = 0; r < 4; ++r)
#pragma unroll
        for (int c = 0; c < 4; ++c)
            acc[r][c] = (floatx4){0.f, 0.f, 0.f, 0.f};

    for (int kb = 0; kb < KSTEPS; ++kb) {
        const int k0 = kb * 32;
        unsigned short av[16];
        if (GATHER) {
            if (avalid) {
                const float4* p = (const float4*)(ArowF + k0 + ahalf * 16);
                float4 f0 = p[0], f1 = p[1], f2 = p[2], f3 = p[3];
                const float fa[16] = {f0.x,f0.y,f0.z,f0.w, f1.x,f1.y,f1.z,f1.w,
                                      f2.x,f2.y,f2.z,f2.w, f3.x,f3.y,f3.z,f3.w};
#pragma unroll
                for (int j = 0; j < 16; ++j) av[j] = f2b(fa[j]);
            } else {
#pragma unroll
                for (int j = 0; j < 16; ++j) av[j] = 0;
            }
        } else {
            const int4* p = (const int4*)(ArowH + k0 + ahalf * 16);
            *(int4*)(av)     = p[0];
            *(int4*)(av + 8) = p[1];
        }
        unsigned short bv[16];
        {
            const float4* q = (const float4*)(Bptr + (size_t)k0 * N);
            float4 f0 = q[0], f1 = q[1], f2 = q[2], f3 = q[3];
            const float fb[16] = {f0.x,f0.y,f0.z,f0.w, f1.x,f1.y,f1.z,f1.w,
                                  f2.x,f2.y,f2.z,f2.w, f3.x,f3.y,f3.z,f3.w};
#pragma unroll
            for (int j = 0; j < 16; ++j) bv[j] = f2b(fb[j]);
        }

        *(int4*)&As[arow * 40 + ahalf * 16]     = *(int4*)(av);
        *(int4*)&As[arow * 40 + ahalf * 16 + 8] = *(int4*)(av + 8);
        *(int4*)&Bs[bk * 136 + bn0]             = *(int4*)(bv);
        *(int4*)&Bs[bk * 136 + bn0 + 8]         = *(int4*)(bv + 8);
        __syncthreads();

        short8 af[4];
#pragma unroll
        for (int r = 0; r < 4; ++r)
            af[r] = *(const short8*)&As[(wr * 64 + r * 16 + l15) * 40 + quad * 8];
        short8 bfr[4];
#pragma unroll
        for (int c = 0; c < 4; ++c) {
#pragma unroll
            for (int j = 0; j < 8; ++j)
                bfr[c][j] = (short)Bs[(quad * 8 + j) * 136 + wc * 64 + c * 16 + l15];
        }
#pragma unroll
        for (int r = 0; r < 4; ++r)
#pragma unroll
            for (int c = 0; c < 4; ++c)
                acc[r][c] = __builtin_amdgcn_mfma_f32_16x16x32_bf16(af[r], bfr[c], acc[r][c], 0, 0, 0);
        __syncthreads();
    }

#pragma unroll
    for (int r = 0; r < 4; ++r) {
#pragma unroll
        for (int reg = 0; reg < 4; ++reg) {
            const int gi = ib + wr * 64 + r * 16 + quad * 4 + reg;
            if (SCATTER) {
                const int slot = e * CAP + gi;
                const int tok = slot_token[slot];
                if (tok >= 0) {
                    const float gsc = slot_gate[slot];
                    float* Out = (float*)Outv;
#pragma unroll
                    for (int c = 0; c < 4; ++c) {
                        const int gn = nb + wc * 64 + c * 16 + l15;
                        Out[(size_t)tok * N + gn] = gsc * acc[r][c][reg];
                    }
                }
            } else {
                unsigned short* Out = (unsigned short*)Outv;
#pragma unroll
                for (int c = 0; c < 4; ++c) {
                    const int gn = nb + wc * 64 + c * 16 + l15;
                    Out[((size_t)e * CAP + gi) * N + gn] = f2b(fmaxf(acc[r][c][reg], 0.f));
                }
            }
        }
    }
}

extern "C" void kernel_launch(void* const* d_in, const int* in_sizes, int n_in,
                              void* d_out, int out_size, void* d_ws, size_t ws_size,
                              hipStream_t stream)
{
    const float* x  = (const float*)d_in[0];   // [8192,1024] fp32
    const float* wg = (const float*)d_in[1];   // [1024,8]    fp32
    const float* w1 = (const float*)d_in[2];   // [8,1024,4096] fp32
    const float* w2 = (const float*)d_in[3];   // [8,4096,1024] fp32
    float* out = (float*)d_out;                // 8388608 out + 1 l_aux, fp32

    char* ws = (char*)d_ws;
    float* gates8       = (float*)(ws);                 // 256 KB
    int*   token_expert = (int*)(ws + 262144);          // 32 KB
    int*   slot_token   = (int*)(ws + 294912);          // 32 KB
    float* slot_gate    = (float*)(ws + 327680);        // 32 KB

    hipMemsetAsync(d_out, 0, (size_t)out_size * 4, stream);
    gate_kernel<<<dim3(S_TOK / 4), dim3(256), 0, stream>>>(x, wg, gates8, token_expert);
    scan_kernel<<<dim3(1), dim3(256), 0, stream>>>(gates8, token_expert, slot_token, slot_gate,
                                                   out + (size_t)S_TOK * MDIM);

    const size_t FAST_NEED = 151355392ull;  // small(352K) + xd(16M) + h(64M) + W(64M)
    if (ws_size >= FAST_NEED) {
        unsigned short* xd = (unsigned short*)(ws + 360448);     // [8192,1024] bf16
        unsigned short* h  = (unsigned short*)(ws + 17137664);   // [8,1024,4096] bf16
        unsigned short* W  = (unsigned short*)(ws + 84246528);   // wT buffer, 64 MB

        dispatch_cvt<<<dim3(EXP * CAP), dim3(256), 0, stream>>>(x, slot_token, xd);
        // w1 [e][1024][4096] -> W [e][4096][1024]
        transpose_cvt<<<dim3(HDIM / 64, MDIM / 64, EXP), dim3(256), 0, stream>>>(w1, W, MDIM, HDIM);
        ffn_gemm_fast<32, HDIM, false><<<dim3(HDIM / 128, CAP / 128, EXP), dim3(256), 0, stream>>>(
            xd, W, h, slot_token, slot_gate);
        // w2 [e][4096][1024] -> W [e][1024][4096]
        transpose_cvt<<<dim3(MDIM / 64, HDIM / 64, EXP), dim3(256), 0, stream>>>(w2, W, HDIM, MDIM);
        ffn_gemm_fast<128, MDIM, true><<<dim3(MDIM / 128, CAP / 128, EXP), dim3(256), 0, stream>>>(
            h, W, out, slot_token, slot_gate);
    } else {
        unsigned short* h = (unsigned short*)(ws + 360448);      // [8,1024,4096] bf16
        ffn_gemm_slow<32, HDIM, true, false><<<dim3(HDIM / 128, CAP / 128, EXP), dim3(256), 0, stream>>>(
            x, w1, h, slot_token, slot_gate);
        ffn_gemm_slow<128, MDIM, false, true><<<dim3(MDIM / 128, CAP / 128, EXP), dim3(256), 0, stream>>>(
            h, w2, out, slot_token, slot_gate);
    }
}